// Round 21
// baseline (114.876 us; speedup 1.0000x reference)
//
#include <hip/hip_runtime.h>

typedef __attribute__((ext_vector_type(8))) short bfrag8;    // 8 bf16 (4 VGPRs)
typedef __attribute__((ext_vector_type(4))) short bfrag4;    // 4 bf16 (2 VGPRs)
typedef __attribute__((ext_vector_type(16))) float f32x16;   // 32x32 MFMA acc

#define B_ 16
#define C_ 64
#define H_ 128
#define W_ 128
#define E_ 4
#define HW_ (H_ * W_)

// ring geometry: 64-px half-rows, 66 slots (px-1..64 rel), 8 ci-chunks of 8
#define NSL 66
#define PLANE2 (NSL * 16)       // 1056 B
#define ROWB2  (8 * PLANE2)     // 8448 B
#define RGK 8                   // output rows per block (512 blocks, 2/CU)

// ---- fast-path ws layout (bytes) ----
// wT2: bf16 MFMA A-fragment layout [e][tap][ch][kb][lane64][8]
#define WT_ELEMS (4 * 9 * 2 * 4 * 64 * 8)      // 147,456 bf16
#define OFF_POOL (WT_ELEMS * 2)
#define OFF_EW   (OFF_POOL + 1024 * 4)
#define WS_NEEDED ((size_t)(OFF_EW + 64 * 4))

// ---- fallback ws layout (floats) ----
#define FB_WT_OFF 0
#define FB_POOLED_OFF 147456
#define FB_EW_OFF 148480

__device__ inline unsigned short f2bf(float f) {
    unsigned u = __builtin_bit_cast(unsigned, f);
    unsigned r = u + 0x7FFFu + ((u >> 16) & 1u);
    return (unsigned short)(r >> 16);
}
__device__ inline float bf2f(unsigned short s) {
    return __builtin_bit_cast(float, (unsigned)s << 16);
}

// ---------------- pool (per (b,c) block) + fused weight convert to frag layout ----------------
__global__ __launch_bounds__(256) void pool_wcvt(const float* __restrict__ in,
                                                 const float* __restrict__ cw,
                                                 float* __restrict__ pooled,
                                                 unsigned short* __restrict__ wT2) {
    if (blockIdx.x < 576) {
        const int idx = blockIdx.x * 256 + threadIdx.x;   // 0..147455
        const int j = idx & 7;
        const int l = (idx >> 3) & 63;
        const int f = idx >> 9;          // frag 0..287 = ((e*9+tap)*2+ch)*4+kb
        const int kb = f & 3;
        const int chh = (f >> 2) & 1;
        const int et = f >> 3;
        const int tap = et % 9;
        const int e = et / 9;
        const int co = chh * 32 + (l & 31);
        const int ci = kb * 16 + (l >> 5) * 8 + j;
        wT2[idx] = f2bf(cw[(((e * C_ + co) * C_ + ci) * 9) + tap]);
    }
    const int bc = blockIdx.x;
    const float* p = in + (size_t)bc * HW_;
    float s = 0.f;
    for (int i = threadIdx.x; i < HW_ / 4; i += 256) {
        float4 v = ((const float4*)p)[i];
        s += v.x + v.y + v.z + v.w;
    }
    for (int off = 32; off; off >>= 1) s += __shfl_down(s, off);
    __shared__ float red[4];
    const int lane = threadIdx.x & 63, wv = threadIdx.x >> 6;
    if (lane == 0) red[wv] = s;
    __syncthreads();
    if (threadIdx.x == 0)
        pooled[bc] = (red[0] + red[1] + red[2] + red[3]) * (1.0f / (float)HW_);
}

// ---------------- gate (fallback path only; fast path folds gate into conv) ----------------
__global__ void gate_kernel(const float* __restrict__ pooled,
                            const float* __restrict__ gate_w,
                            const float* __restrict__ gate_b,
                            float* __restrict__ ew) {
    const int b = threadIdx.x;
    if (b >= B_) return;
    float lg[E_];
    for (int e = 0; e < E_; e++) {
        float s = gate_b[e];
        for (int c = 0; c < C_; c++) s += pooled[b * C_ + c] * gate_w[e * C_ + c];
        lg[e] = s;
    }
    float m = fmaxf(fmaxf(lg[0], lg[1]), fmaxf(lg[2], lg[3]));
    float ex[E_], sum = 0.f;
    for (int e = 0; e < E_; e++) { ex[e] = expf(lg[e] - m); sum += ex[e]; }
    for (int e = 0; e < E_; e++) ex[e] /= sum;
    int i1 = 0;
    for (int e = 1; e < E_; e++) if (ex[e] > ex[i1]) i1 = e;
    int i2 = -1;
    for (int e = 0; e < E_; e++) {
        if (e == i1) continue;
        if (i2 < 0 || ex[e] > ex[i2]) i2 = e;
    }
    for (int e = 0; e < E_; e++)
        ew[b * E_ + e] = (e == i1 || e == i2) ? ex[e] : 0.f;
}

// ---------------- conv: r10 structure (best measured, 70us) at 4 waves/SIMD ----------------
// r10's ei-split pbuf dataflow, unchanged, but: 512 blocks (= 2/CU) x RGK=8
// instead of 256 x 16, gate fused into prologue, launch_bounds(512,2)
// (cap 128 = r10's measured VGPR -> 4 waves/SIMD, double r10's TLP).
// 8 waves = ei(2: expert) x ch(2: co half) x pq(2: 32-px quarter); wave
// computes 32co x 32px x ONE expert (1 acc). e1-waves -> fp32 pbuf after B1;
// e0-waves combine resid(ring)+own+pbuf after B2. LDS 41.7 KB -> 2 blocks/CU.
__global__ __launch_bounds__(512, 2) void conv_f(const float* __restrict__ in,
                                                 const float* __restrict__ kk,
                                                 const float* __restrict__ cb,
                                                 const float* __restrict__ pooled,
                                                 const float* __restrict__ gw,
                                                 const float* __restrict__ gb,
                                                 const unsigned short* __restrict__ wT2,
                                                 float* __restrict__ out) {
    const int raw = blockIdx.x;                    // 512 blocks
    const int swz = (raw & 7) * 64 + (raw >> 3);   // XCD-bijective (512 % 8 == 0)
    const int b   = swz >> 5;
    const int pxh = (swz >> 4) & 1;
    const int h0  = (swz & 15) * RGK;
    const int x0g = pxh * 64;

    const int tid = threadIdx.x;
    const int lane = tid & 63;
    const int wv = tid >> 6;          // 0..7
    const int ln = lane & 31;
    const int lh = lane >> 5;
    const int ei = wv >> 2;           // expert slot (0 -> e0, 1 -> e1)
    const int ch = (wv >> 1) & 1;     // co half
    const int pq = wv & 1;            // 32-px quarter within the 64-px half
    const int co0 = ch * 32;

    const int spx = tid & 63;         // staging px (slot spx+1)
    const int scg = tid >> 6;         // staging ci-chunk (8 ci)

    __shared__ __align__(16) char ring[3 * ROWB2];   // 25,344 B
    __shared__ float pbuf[2 * 2 * 32 * 32];          // 16,384 B [ch][pq][co32][px32]
    __shared__ float sEW[E_];

    // ---- gate (wave 0 recomputes; broadcast via LDS) ----
    if (tid < 64) {
        const float p = pooled[b * C_ + lane];
        float part[E_];
#pragma unroll
        for (int e = 0; e < E_; e++) part[e] = p * gw[e * C_ + lane];
#pragma unroll
        for (int off = 32; off; off >>= 1)
#pragma unroll
            for (int e = 0; e < E_; e++) part[e] += __shfl_down(part[e], off);
        if (lane == 0) {
            float lg[E_];
#pragma unroll
            for (int e = 0; e < E_; e++) lg[e] = part[e] + gb[e];
            float m = fmaxf(fmaxf(lg[0], lg[1]), fmaxf(lg[2], lg[3]));
            float ex[E_], sum = 0.f;
#pragma unroll
            for (int e = 0; e < E_; e++) { ex[e] = __expf(lg[e] - m); sum += ex[e]; }
            const float inv = 1.0f / sum;
            int i1 = 0;
            for (int e = 1; e < E_; e++) if (ex[e] > ex[i1]) i1 = e;
            int i2 = -1;
            for (int e = 0; e < E_; e++) {
                if (e == i1) continue;
                if (i2 < 0 || ex[e] > ex[i2]) i2 = e;
            }
#pragma unroll
            for (int e = 0; e < E_; e++)
                sEW[e] = (e == i1 || e == i2) ? ex[e] * inv : 0.f;
        }
    }
    __syncthreads();

    int e0 = 0, e1 = 0; float w0 = 0.f, w1 = 0.f;
    {
        int found = 0;
        for (int e = 0; e < E_; e++) {
            float we = sEW[e];
            if (we != 0.f) {
                if (!found) { e0 = e; w0 = we; found = 1; }
                else        { e1 = e; w1 = we; }
            }
        }
        if (w1 == 0.f) e1 = e0;   // degenerate: w1=0 makes its contribution 0
    }

    const int es = ei ? e1 : e0;      // this wave's expert
    const float ww = ei ? w1 : w0;    // this wave's gate weight
    const float* cbp = cb + es * C_;
    const float* kkp = kk + b * C_;

    float pv[8], ph[8];
    auto STAGE = [&](int r) {
        if ((unsigned)r < (unsigned)H_) {
            const float* src = in + ((size_t)(b * C_ + scg * 8) * H_ + r) * W_ + x0g + spx;
#pragma unroll
            for (int i = 0; i < 8; ++i) pv[i] = src[(size_t)i * HW_];
        } else {
#pragma unroll
            for (int i = 0; i < 8; ++i) pv[i] = 0.f;
        }
        if (tid < 16) {
            const int hp = tid & 1;
            const int cgh = tid >> 1;
            const int pg = hp ? (x0g + 64) : (x0g - 1);
            const bool ok = ((unsigned)r < (unsigned)H_) && ((unsigned)pg < (unsigned)W_);
            const float* src = in + ((size_t)(b * C_ + cgh * 8) * H_ + (((unsigned)r < (unsigned)H_) ? r : 0)) * W_ + (ok ? pg : 0);
#pragma unroll
            for (int i = 0; i < 8; ++i) ph[i] = ok ? src[(size_t)i * HW_] : 0.f;
        }
    };
    auto COMMIT = [&](int rs) {
        bfrag8 f;
#pragma unroll
        for (int i = 0; i < 8; ++i) f[i] = (short)f2bf(pv[i]);
        *(bfrag8*)(ring + rs * ROWB2 + scg * PLANE2 + (spx + 1) * 16) = f;
        if (tid < 16) {
            const int hp = tid & 1, cgh = tid >> 1;
            bfrag8 g;
#pragma unroll
            for (int i = 0; i < 8; ++i) g[i] = (short)f2bf(ph[i]);
            *(bfrag8*)(ring + rs * ROWB2 + cgh * PLANE2 + (hp ? 65 : 0) * 16) = g;
        }
    };

    // prologue: rows h0-1, h0, h0+1 -> slots 0,1,2
    STAGE(h0 - 1); COMMIT(0);
    STAGE(h0);     COMMIT(1);
    STAGE(h0 + 1); COMMIT(2);
    __syncthreads();

    float* pb = pbuf + (ch * 2 + pq) * 1024;

    const char* wb = (const char*)wT2 + (size_t)es * 73728 + ch * 4096 + lane * 16;

    int m0 = 0, m1 = 1, m2 = 2;
    for (int s = 0; s < RGK; ++s) {
        if (s + 1 < RGK) STAGE(h0 + s + 2);   // HBM loads in flight across MFMA

        f32x16 A;
#pragma unroll
        for (int i = 0; i < 16; ++i) A[i] = 0.f;

#pragma unroll
        for (int ky = 0; ky < 3; ++ky) {
            const char* rb = ring + (ky == 0 ? m0 : (ky == 1 ? m1 : m2)) * ROWB2;
#pragma unroll
            for (int kx = 0; kx < 3; ++kx) {
                const int tap = ky * 3 + kx;
#pragma unroll
                for (int kb = 0; kb < 4; ++kb) {
                    bfrag8 bb = *(const bfrag8*)(rb + (kb * 2 + lh) * PLANE2
                                                 + (pq * 32 + ln + kx) * 16);
                    bfrag8 a = *(const bfrag8*)(wb + tap * 8192 + kb * 1024);
                    A = __builtin_amdgcn_mfma_f32_32x32x16_bf16(a, bb, A, 0, 0, 0);
                }
            }
        }

        __syncthreads();                 // B1: all reads of slot m0 done
        if (s + 1 < RGK) COMMIT(m0);     // next row replaces oldest

        const int row = h0 + s;
        if (ei == 1) {
            // finished contribution of expert e1 -> LDS pbuf (fp32)
#pragma unroll
            for (int g = 0; g < 16; ++g) {
                const int cs = (g & 3) + 8 * (g >> 2) + 4 * lh;    // 0..31
                const int co = co0 + cs;
                const float kv = kkp[co];
                pb[cs * 32 + ln] = fmaxf(A[g] + cbp[co], 0.f) * (kv * ww);
            }
        }
        __syncthreads();                 // B2: pbuf + commits visible
        if (ei == 0) {
            const char* rm1 = ring + m1 * ROWB2 + (pq * 32 + ln + 1) * 16 + lh * 8;
            bfrag4 ra[4];
#pragma unroll
            for (int c = 0; c < 4; ++c)
                ra[c] = *(const bfrag4*)(rm1 + (ch * 4 + c) * PLANE2);
#pragma unroll
            for (int g = 0; g < 16; ++g) {
                const int r_ = g & 3, c_ = g >> 2;
                const int cs = r_ + 8 * c_ + 4 * lh;
                const int co = co0 + cs;
                const float kv = kkp[co];
                const size_t oi = ((size_t)(b * C_ + co) * H_ + row) * W_ + x0g + pq * 32 + ln;
                out[oi] = bf2f((unsigned short)ra[c_][r_])
                          + fmaxf(A[g] + cbp[co], 0.f) * (kv * ww)
                          + pb[cs * 32 + ln];
            }
        }
        const int t = m0; m0 = m1; m1 = m2; m2 = t;
    }
}

// ================= fallback (fp32 path, used only if ws too small) =================
#define CHUNK 32

__global__ __launch_bounds__(256) void pool_kernel(const float* __restrict__ in,
                                                   float* __restrict__ pooled) {
    const int bc = blockIdx.x;
    const float* p = in + (size_t)bc * HW_;
    float s = 0.f;
    for (int i = threadIdx.x; i < HW_ / 4; i += 256) {
        float4 v = ((const float4*)p)[i];
        s += v.x + v.y + v.z + v.w;
    }
    for (int off = 32; off; off >>= 1) s += __shfl_down(s, off);
    __shared__ float red[4];
    const int lane = threadIdx.x & 63, wv = threadIdx.x >> 6;
    if (lane == 0) red[wv] = s;
    __syncthreads();
    if (threadIdx.x == 0)
        pooled[bc] = (red[0] + red[1] + red[2] + red[3]) * (1.0f / (float)HW_);
}

__global__ __launch_bounds__(256) void wtr_kernel(const float* __restrict__ cw,
                                                  float* __restrict__ wT) {
    const int idx = blockIdx.x * 256 + threadIdx.x;
    if (idx >= E_ * C_ * 9 * C_) return;
    const int co = idx & 63;
    const int t2 = idx >> 6;
    const int tap = t2 % 9;
    const int t3 = t2 / 9;
    const int ci = t3 & 63;
    const int e = t3 >> 6;
    wT[idx] = cw[(((e * C_ + co) * C_ + ci) * 9) + tap];
}

__global__ __launch_bounds__(512) void conv_fallback(const float* __restrict__ in,
                                                     const float* __restrict__ kk,
                                                     const float* __restrict__ wT,
                                                     const float* __restrict__ cb,
                                                     const float* __restrict__ ew,
                                                     float* __restrict__ out) {
    const int bid = blockIdx.x;
    const int b = bid / H_;
    const int h = bid % H_;
    const int tid = threadIdx.x;
    const int lane = tid & 63;
    const int wv = tid >> 6;
    const int x0 = wv * 16;

    __shared__ float sIn[CHUNK * 3 * W_];

    float w0 = 0.f, w1 = 0.f;
    int e0 = 0, e1 = 0;
    {
        float we[E_];
#pragma unroll
        for (int e = 0; e < E_; e++) we[e] = ew[b * E_ + e];
        int found = 0;
        for (int e = 0; e < E_; e++) {
            if (we[e] != 0.f) {
                if (!found) { e0 = e; w0 = we[e]; found = 1; }
                else        { e1 = e; w1 = we[e]; }
            }
        }
        if (w1 == 0.f) e1 = e0;
    }

    float acc0[16], acc1[16];
#pragma unroll
    for (int i = 0; i < 16; i++) { acc0[i] = 0.f; acc1[i] = 0.f; }

    for (int cblk = 0; cblk < C_ / CHUNK; cblk++) {
        const int cbase = cblk * CHUNK;
        __syncthreads();
        for (int f = tid; f < CHUNK * 3 * W_ / 4; f += 512) {
            const int fi = f * 4;
            const int ci = fi / (3 * W_);
            const int rem = fi - ci * 3 * W_;
            const int kyy = rem / W_;
            const int x = rem - kyy * W_;
            const int hh = h + kyy - 1;
            float4 v = make_float4(0.f, 0.f, 0.f, 0.f);
            if (hh >= 0 && hh < H_)
                v = *(const float4*)(in + ((size_t)(b * C_ + cbase + ci) * H_ + hh) * W_ + x);
            *(float4*)(sIn + fi) = v;
        }
        __syncthreads();

        const float* wp0 = wT + (size_t)((e0 * C_ + cbase) * 9) * C_ + lane;
        const float* wp1 = wT + (size_t)((e1 * C_ + cbase) * 9) * C_ + lane;
        for (int ci = 0; ci < CHUNK; ci++) {
            float wa[9], wb[9];
#pragma unroll
            for (int t = 0; t < 9; t++) {
                wa[t] = wp0[(ci * 9 + t) * C_];
                wb[t] = wp1[(ci * 9 + t) * C_];
            }
            const float* rowp = sIn + ci * 3 * W_;
#pragma unroll
            for (int kyy = 0; kyy < 3; kyy++) {
                float xin[18];
                const float* rp = rowp + kyy * W_ + x0;
                xin[0] = (x0 == 0) ? 0.f : rp[-1];
#pragma unroll
                for (int j = 0; j < 16; j += 4) {
                    float4 v = *(const float4*)(rp + j);
                    xin[1 + j] = v.x; xin[2 + j] = v.y; xin[3 + j] = v.z; xin[4 + j] = v.w;
                }
                xin[17] = (x0 + 16 >= W_) ? 0.f : rp[16];
                const int t0 = kyy * 3;
#pragma unroll
                for (int x = 0; x < 16; x++) {
                    acc0[x] += xin[x] * wa[t0] + xin[x + 1] * wa[t0 + 1] + xin[x + 2] * wa[t0 + 2];
                    acc1[x] += xin[x] * wb[t0] + xin[x + 1] * wb[t0 + 1] + xin[x + 2] * wb[t0 + 2];
                }
            }
        }
    }

    const float kv = kk[b * C_ + lane];
    const float b0v = cb[e0 * C_ + lane];
    const float b1v = cb[e1 * C_ + lane];
    const float kw0 = kv * w0, kw1 = kv * w1;
    const size_t obase = ((size_t)(b * C_ + lane) * H_ + h) * W_ + x0;
#pragma unroll
    for (int x = 0; x < 16; x += 4) {
        float4 iv = *(const float4*)(in + obase + x);
        float4 ov;
        ov.x = iv.x + fmaxf(acc0[x + 0] + b0v, 0.f) * kw0 + fmaxf(acc1[x + 0] + b1v, 0.f) * kw1;
        ov.y = iv.y + fmaxf(acc0[x + 1] + b0v, 0.f) * kw0 + fmaxf(acc1[x + 1] + b1v, 0.f) * kw1;
        ov.z = iv.z + fmaxf(acc0[x + 2] + b0v, 0.f) * kw0 + fmaxf(acc1[x + 2] + b1v, 0.f) * kw1;
        ov.w = iv.w + fmaxf(acc0[x + 3] + b0v, 0.f) * kw0 + fmaxf(acc1[x + 3] + b1v, 0.f) * kw1;
        *(float4*)(out + obase + x) = ov;
    }
}

extern "C" void kernel_launch(void* const* d_in, const int* in_sizes, int n_in,
                              void* d_out, int out_size, void* d_ws, size_t ws_size,
                              hipStream_t stream) {
    const float* inputs = (const float*)d_in[0];
    const float* k      = (const float*)d_in[1];
    const float* gate_w = (const float*)d_in[2];
    const float* gate_b = (const float*)d_in[3];
    const float* conv_w = (const float*)d_in[4];
    const float* conv_b = (const float*)d_in[5];
    float* out = (float*)d_out;
    char* wsb = (char*)d_ws;

    if (ws_size >= WS_NEEDED) {
        unsigned short* wT2 = (unsigned short*)wsb;
        float* pooled = (float*)(wsb + OFF_POOL);

        pool_wcvt<<<B_ * C_, 256, 0, stream>>>(inputs, conv_w, pooled, wT2);
        conv_f<<<512, 512, 0, stream>>>(inputs, k, conv_b, pooled,
                                        gate_w, gate_b, wT2, out);
    } else {
        float* ws = (float*)d_ws;
        float* wTf    = ws + FB_WT_OFF;
        float* pooled = ws + FB_POOLED_OFF;
        float* ewbuf  = ws + FB_EW_OFF;

        pool_kernel<<<B_ * C_, 256, 0, stream>>>(inputs, pooled);
        gate_kernel<<<1, 64, 0, stream>>>(pooled, gate_w, gate_b, ewbuf);
        wtr_kernel<<<(E_ * C_ * 9 * C_ + 255) / 256, 256, 0, stream>>>(conv_w, wTf);
        conv_fallback<<<B_ * H_, 512, 0, stream>>>(inputs, k, wTf, conv_b, ewbuf, out);
    }
}

// Round 22
// 82.494 us; speedup vs baseline: 1.3925x; 1.3925x over previous
//
#include <hip/hip_runtime.h>

typedef __attribute__((ext_vector_type(8))) short bfrag8;    // 8 bf16 (4 VGPRs)
typedef __attribute__((ext_vector_type(4))) short bfrag4;    // 4 bf16 (2 VGPRs)
typedef __attribute__((ext_vector_type(16))) float f32x16;   // 32x32 MFMA acc

#define B_ 16
#define C_ 64
#define H_ 128
#define W_ 128
#define E_ 4
#define HW_ (H_ * W_)

// ring geometry: 64-px half-rows, 66 slots (px-1..64 rel), 8 ci-chunks of 8
#define NSL 66
#define PLANE2 (NSL * 16)       // 1056 B
#define ROWB2  (8 * PLANE2)     // 8448 B
#define RG 4                    // output rows per block (1024 blocks, 4/CU)

// ---- fast-path ws layout (bytes) ----
// wT2: bf16 MFMA A-fragment layout [e][tap][ch][kb][lane64][8]
#define WT_ELEMS (4 * 9 * 2 * 4 * 64 * 8)      // 147,456 bf16
#define OFF_POOL (WT_ELEMS * 2)
#define OFF_EW   (OFF_POOL + 1024 * 4)
#define WS_NEEDED ((size_t)(OFF_EW + 64 * 4))

// ---- fallback ws layout (floats) ----
#define FB_WT_OFF 0
#define FB_POOLED_OFF 147456
#define FB_EW_OFF 148480

__device__ inline unsigned short f2bf(float f) {
    unsigned u = __builtin_bit_cast(unsigned, f);
    unsigned r = u + 0x7FFFu + ((u >> 16) & 1u);
    return (unsigned short)(r >> 16);
}
__device__ inline float bf2f(unsigned short s) {
    return __builtin_bit_cast(float, (unsigned)s << 16);
}

// ---------------- pool (per (b,c) block) + fused weight convert to frag layout ----------------
__global__ __launch_bounds__(256) void pool_wcvt(const float* __restrict__ in,
                                                 const float* __restrict__ cw,
                                                 float* __restrict__ pooled,
                                                 unsigned short* __restrict__ wT2) {
    if (blockIdx.x < 576) {
        const int idx = blockIdx.x * 256 + threadIdx.x;   // 0..147455
        const int j = idx & 7;
        const int l = (idx >> 3) & 63;
        const int f = idx >> 9;          // frag 0..287 = ((e*9+tap)*2+ch)*4+kb
        const int kb = f & 3;
        const int chh = (f >> 2) & 1;
        const int et = f >> 3;
        const int tap = et % 9;
        const int e = et / 9;
        const int co = chh * 32 + (l & 31);
        const int ci = kb * 16 + (l >> 5) * 8 + j;
        wT2[idx] = f2bf(cw[(((e * C_ + co) * C_ + ci) * 9) + tap]);
    }
    const int bc = blockIdx.x;
    const float* p = in + (size_t)bc * HW_;
    float s = 0.f;
    for (int i = threadIdx.x; i < HW_ / 4; i += 256) {
        float4 v = ((const float4*)p)[i];
        s += v.x + v.y + v.z + v.w;
    }
    for (int off = 32; off; off >>= 1) s += __shfl_down(s, off);
    __shared__ float red[4];
    const int lane = threadIdx.x & 63, wv = threadIdx.x >> 6;
    if (lane == 0) red[wv] = s;
    __syncthreads();
    if (threadIdx.x == 0)
        pooled[bc] = (red[0] + red[1] + red[2] + red[3]) * (1.0f / (float)HW_);
}

// ---------------- gate (fallback path only; fast path folds gate into conv) ----------------
__global__ void gate_kernel(const float* __restrict__ pooled,
                            const float* __restrict__ gate_w,
                            const float* __restrict__ gate_b,
                            float* __restrict__ ew) {
    const int b = threadIdx.x;
    if (b >= B_) return;
    float lg[E_];
    for (int e = 0; e < E_; e++) {
        float s = gate_b[e];
        for (int c = 0; c < C_; c++) s += pooled[b * C_ + c] * gate_w[e * C_ + c];
        lg[e] = s;
    }
    float m = fmaxf(fmaxf(lg[0], lg[1]), fmaxf(lg[2], lg[3]));
    float ex[E_], sum = 0.f;
    for (int e = 0; e < E_; e++) { ex[e] = expf(lg[e] - m); sum += ex[e]; }
    for (int e = 0; e < E_; e++) ex[e] /= sum;
    int i1 = 0;
    for (int e = 1; e < E_; e++) if (ex[e] > ex[i1]) i1 = e;
    int i2 = -1;
    for (int e = 0; e < E_; e++) {
        if (e == i1) continue;
        if (i2 < 0 || ex[e] > ex[i2]) i2 = e;
    }
    for (int e = 0; e < E_; e++)
        ew[b * E_ + e] = (e == i1 || e == i2) ? ex[e] : 0.f;
}

// ---------------- conv: 4-slot ring, ONE barrier/step, 4 blocks/CU, unroll-1 ----------------
// Session optimum (r16): 4-slot ring with single end-of-step barrier; 1024
// blocks = img(16) x pxhalf(2) x rowgroup(32 x RG=4); 4 waves = ch(2) x pq(2);
// wave tile 32co x 32px x 2 experts. `#pragma unroll 1` on ky/kx caps
// in-flight A-fragments (~12) -> VGPR 104, zero spill. Gate fused (wave 0).
__global__ __launch_bounds__(256, 2) void conv_p4(const float* __restrict__ in,
                                                  const float* __restrict__ kk,
                                                  const float* __restrict__ cb,
                                                  const float* __restrict__ pooled,
                                                  const float* __restrict__ gw,
                                                  const float* __restrict__ gb,
                                                  const unsigned short* __restrict__ wT2,
                                                  float* __restrict__ out) {
    const int raw = blockIdx.x;                     // 1024 blocks
    const int swz = (raw & 7) * 128 + (raw >> 3);   // XCD-bijective (1024 % 8 == 0)
    const int b   = swz >> 6;                       // 64 blocks per image
    const int pxh = (swz >> 5) & 1;
    const int h0  = (swz & 31) * RG;
    const int x0g = pxh * 64;

    const int tid = threadIdx.x;
    const int lane = tid & 63;
    const int wv = tid >> 6;          // 0..3
    const int ln = lane & 31;
    const int lh = lane >> 5;
    const int ch = wv & 1;            // co half
    const int pq = wv >> 1;           // 32-px quarter within the 64-px half
    const int co0 = ch * 32;

    const int spx = tid & 63;         // staging px (slot spx+1)
    const int scg = tid >> 6;         // staging ci-group of 16

    __shared__ __align__(16) char ring[4 * ROWB2];   // 33,792 B
    __shared__ float sEW[E_];

    // ---- gate (wave 0 recomputes; broadcast via LDS) ----
    if (tid < 64) {
        const float p = pooled[b * C_ + lane];
        float part[E_];
#pragma unroll
        for (int e = 0; e < E_; e++) part[e] = p * gw[e * C_ + lane];
#pragma unroll
        for (int off = 32; off; off >>= 1)
#pragma unroll
            for (int e = 0; e < E_; e++) part[e] += __shfl_down(part[e], off);
        if (lane == 0) {
            float lg[E_];
#pragma unroll
            for (int e = 0; e < E_; e++) lg[e] = part[e] + gb[e];
            float m = fmaxf(fmaxf(lg[0], lg[1]), fmaxf(lg[2], lg[3]));
            float ex[E_], sum = 0.f;
#pragma unroll
            for (int e = 0; e < E_; e++) { ex[e] = __expf(lg[e] - m); sum += ex[e]; }
            const float inv = 1.0f / sum;
            int i1 = 0;
            for (int e = 1; e < E_; e++) if (ex[e] > ex[i1]) i1 = e;
            int i2 = -1;
            for (int e = 0; e < E_; e++) {
                if (e == i1) continue;
                if (i2 < 0 || ex[e] > ex[i2]) i2 = e;
            }
#pragma unroll
            for (int e = 0; e < E_; e++)
                sEW[e] = (e == i1 || e == i2) ? ex[e] * inv : 0.f;
        }
    }
    __syncthreads();

    int e0 = 0, e1 = 0; float w0 = 0.f, w1 = 0.f;
    {
        int found = 0;
        for (int e = 0; e < E_; e++) {
            float we = sEW[e];
            if (we != 0.f) {
                if (!found) { e0 = e; w0 = we; found = 1; }
                else        { e1 = e; w1 = we; }
            }
        }
        if (w1 == 0.f) e1 = e0;   // degenerate: w1=0 zeroes its contribution
    }

    const float* cb0 = cb + e0 * C_;
    const float* cb1 = cb + e1 * C_;
    const float* kkp = kk + b * C_;

    float pv[16], ph[8];
    auto STAGE = [&](int r) {
        if ((unsigned)r < (unsigned)H_) {
            const float* src = in + ((size_t)(b * C_ + scg * 16) * H_ + r) * W_ + x0g + spx;
#pragma unroll
            for (int i = 0; i < 16; ++i) pv[i] = src[(size_t)i * HW_];
        } else {
#pragma unroll
            for (int i = 0; i < 16; ++i) pv[i] = 0.f;
        }
        if (tid < 16) {
            const int hp = tid & 1;
            const int cgh = tid >> 1;
            const int pg = hp ? (x0g + 64) : (x0g - 1);
            const bool ok = ((unsigned)r < (unsigned)H_) && ((unsigned)pg < (unsigned)W_);
            const float* src = in + ((size_t)(b * C_ + cgh * 8) * H_ + (((unsigned)r < (unsigned)H_) ? r : 0)) * W_ + (ok ? pg : 0);
#pragma unroll
            for (int i = 0; i < 8; ++i) ph[i] = ok ? src[(size_t)i * HW_] : 0.f;
        }
    };
    auto COMMIT = [&](int rs) {
        bfrag8 f0, f1;
#pragma unroll
        for (int j = 0; j < 8; ++j) {
            f0[j] = (short)f2bf(pv[j]);
            f1[j] = (short)f2bf(pv[8 + j]);
        }
        char* bp = ring + rs * ROWB2 + (spx + 1) * 16;
        *(bfrag8*)(bp + (scg * 2) * PLANE2) = f0;
        *(bfrag8*)(bp + (scg * 2 + 1) * PLANE2) = f1;
        if (tid < 16) {
            const int hp = tid & 1, cgh = tid >> 1;
            bfrag8 g;
#pragma unroll
            for (int i = 0; i < 8; ++i) g[i] = (short)f2bf(ph[i]);
            *(bfrag8*)(ring + rs * ROWB2 + cgh * PLANE2 + (hp ? 65 : 0) * 16) = g;
        }
    };

    // prologue: rows h0-1, h0, h0+1 -> slots 0,1,2  (slot(h0-1+j) = j&3)
    STAGE(h0 - 1); COMMIT(0);
    STAGE(h0);     COMMIT(1);
    STAGE(h0 + 1); COMMIT(2);
    __syncthreads();

    const char* wb0 = (const char*)wT2 + (size_t)e0 * 73728 + ch * 4096 + lane * 16;
    const char* wb1 = (const char*)wT2 + (size_t)e1 * 73728 + ch * 4096 + lane * 16;

    for (int s = 0; s < RG; ++s) {
        if (s + 1 < RG) STAGE(h0 + s + 2);   // loads in flight across MFMA phase

        f32x16 Ae0, Ae1;                      // expert e0 / e1, 32co x 32px
#pragma unroll
        for (int i = 0; i < 16; ++i) { Ae0[i] = 0.f; Ae1[i] = 0.f; }

#pragma unroll 1
        for (int ky = 0; ky < 3; ++ky) {
            const char* rb = ring + ((s + ky) & 3) * ROWB2;   // rows h0+s-1+ky
            const char* wk0 = wb0 + ky * 24576;
            const char* wk1 = wb1 + ky * 24576;
#pragma unroll 1
            for (int kx = 0; kx < 3; ++kx) {
#pragma unroll
                for (int kb = 0; kb < 4; ++kb) {
                    bfrag8 a0 = *(const bfrag8*)(wk0 + kx * 8192 + kb * 1024);
                    bfrag8 a1 = *(const bfrag8*)(wk1 + kx * 8192 + kb * 1024);
                    bfrag8 bb = *(const bfrag8*)(rb + (kb * 2 + lh) * PLANE2
                                                 + (pq * 32 + ln + kx) * 16);
                    Ae0 = __builtin_amdgcn_mfma_f32_32x32x16_bf16(a0, bb, Ae0, 0, 0, 0);
                    Ae1 = __builtin_amdgcn_mfma_f32_32x32x16_bf16(a1, bb, Ae1, 0, 0, 0);
                }
            }
        }

        // commit row h0+s+2 into slot (s+3)&3 — unread during this step
        if (s + 1 < RG) COMMIT((s + 3) & 3);

        // epilogue: out = resid(bf16, slot (s+1)&3) + relu(a+b0)*k*w0 + relu(a+b1)*k*w1
        const int row = h0 + s;
        const char* rm1 = ring + ((s + 1) & 3) * ROWB2 + (pq * 32 + ln + 1) * 16 + lh * 8;
        bfrag4 ra[4];
#pragma unroll
        for (int c = 0; c < 4; ++c)
            ra[c] = *(const bfrag4*)(rm1 + (ch * 4 + c) * PLANE2);
#pragma unroll
        for (int g = 0; g < 16; ++g) {
            const int r_ = g & 3, c_ = g >> 2;
            const int co = co0 + r_ + 8 * c_ + 4 * lh;
            const float kv = kkp[co];
            const size_t oi = ((size_t)(b * C_ + co) * H_ + row) * W_ + x0g + pq * 32 + ln;
            out[oi] = bf2f((unsigned short)ra[c_][r_])
                      + fmaxf(Ae0[g] + cb0[co], 0.f) * (kv * w0)
                      + fmaxf(Ae1[g] + cb1[co], 0.f) * (kv * w1);
        }

        __syncthreads();   // single barrier: commits visible; slot (s+4)&3 safe to overwrite
    }
}

// ================= fallback (fp32 path, used only if ws too small) =================
#define CHUNK 32

__global__ __launch_bounds__(256) void pool_kernel(const float* __restrict__ in,
                                                   float* __restrict__ pooled) {
    const int bc = blockIdx.x;
    const float* p = in + (size_t)bc * HW_;
    float s = 0.f;
    for (int i = threadIdx.x; i < HW_ / 4; i += 256) {
        float4 v = ((const float4*)p)[i];
        s += v.x + v.y + v.z + v.w;
    }
    for (int off = 32; off; off >>= 1) s += __shfl_down(s, off);
    __shared__ float red[4];
    const int lane = threadIdx.x & 63, wv = threadIdx.x >> 6;
    if (lane == 0) red[wv] = s;
    __syncthreads();
    if (threadIdx.x == 0)
        pooled[bc] = (red[0] + red[1] + red[2] + red[3]) * (1.0f / (float)HW_);
}

__global__ __launch_bounds__(256) void wtr_kernel(const float* __restrict__ cw,
                                                  float* __restrict__ wT) {
    const int idx = blockIdx.x * 256 + threadIdx.x;
    if (idx >= E_ * C_ * 9 * C_) return;
    const int co = idx & 63;
    const int t2 = idx >> 6;
    const int tap = t2 % 9;
    const int t3 = t2 / 9;
    const int ci = t3 & 63;
    const int e = t3 >> 6;
    wT[idx] = cw[(((e * C_ + co) * C_ + ci) * 9) + tap];
}

__global__ __launch_bounds__(512) void conv_fallback(const float* __restrict__ in,
                                                     const float* __restrict__ kk,
                                                     const float* __restrict__ wT,
                                                     const float* __restrict__ cb,
                                                     const float* __restrict__ ew,
                                                     float* __restrict__ out) {
    const int bid = blockIdx.x;
    const int b = bid / H_;
    const int h = bid % H_;
    const int tid = threadIdx.x;
    const int lane = tid & 63;
    const int wv = tid >> 6;
    const int x0 = wv * 16;

    __shared__ float sIn[CHUNK * 3 * W_];

    float w0 = 0.f, w1 = 0.f;
    int e0 = 0, e1 = 0;
    {
        float we[E_];
#pragma unroll
        for (int e = 0; e < E_; e++) we[e] = ew[b * E_ + e];
        int found = 0;
        for (int e = 0; e < E_; e++) {
            if (we[e] != 0.f) {
                if (!found) { e0 = e; w0 = we[e]; found = 1; }
                else        { e1 = e; w1 = we[e]; }
            }
        }
        if (w1 == 0.f) e1 = e0;
    }

    float acc0[16], acc1[16];
#pragma unroll
    for (int i = 0; i < 16; i++) { acc0[i] = 0.f; acc1[i] = 0.f; }

    for (int cblk = 0; cblk < C_ / CHUNK; cblk++) {
        const int cbase = cblk * CHUNK;
        __syncthreads();
        for (int f = tid; f < CHUNK * 3 * W_ / 4; f += 512) {
            const int fi = f * 4;
            const int ci = fi / (3 * W_);
            const int rem = fi - ci * 3 * W_;
            const int kyy = rem / W_;
            const int x = rem - kyy * W_;
            const int hh = h + kyy - 1;
            float4 v = make_float4(0.f, 0.f, 0.f, 0.f);
            if (hh >= 0 && hh < H_)
                v = *(const float4*)(in + ((size_t)(b * C_ + cbase + ci) * H_ + hh) * W_ + x);
            *(float4*)(sIn + fi) = v;
        }
        __syncthreads();

        const float* wp0 = wT + (size_t)((e0 * C_ + cbase) * 9) * C_ + lane;
        const float* wp1 = wT + (size_t)((e1 * C_ + cbase) * 9) * C_ + lane;
        for (int ci = 0; ci < CHUNK; ci++) {
            float wa[9], wb[9];
#pragma unroll
            for (int t = 0; t < 9; t++) {
                wa[t] = wp0[(ci * 9 + t) * C_];
                wb[t] = wp1[(ci * 9 + t) * C_];
            }
            const float* rowp = sIn + ci * 3 * W_;
#pragma unroll
            for (int kyy = 0; kyy < 3; kyy++) {
                float xin[18];
                const float* rp = rowp + kyy * W_ + x0;
                xin[0] = (x0 == 0) ? 0.f : rp[-1];
#pragma unroll
                for (int j = 0; j < 16; j += 4) {
                    float4 v = *(const float4*)(rp + j);
                    xin[1 + j] = v.x; xin[2 + j] = v.y; xin[3 + j] = v.z; xin[4 + j] = v.w;
                }
                xin[17] = (x0 + 16 >= W_) ? 0.f : rp[16];
                const int t0 = kyy * 3;
#pragma unroll
                for (int x = 0; x < 16; x++) {
                    acc0[x] += xin[x] * wa[t0] + xin[x + 1] * wa[t0 + 1] + xin[x + 2] * wa[t0 + 2];
                    acc1[x] += xin[x] * wb[t0] + xin[x + 1] * wb[t0 + 1] + xin[x + 2] * wb[t0 + 2];
                }
            }
        }
    }

    const float kv = kk[b * C_ + lane];
    const float b0v = cb[e0 * C_ + lane];
    const float b1v = cb[e1 * C_ + lane];
    const float kw0 = kv * w0, kw1 = kv * w1;
    const size_t obase = ((size_t)(b * C_ + lane) * H_ + h) * W_ + x0;
#pragma unroll
    for (int x = 0; x < 16; x += 4) {
        float4 iv = *(const float4*)(in + obase + x);
        float4 ov;
        ov.x = iv.x + fmaxf(acc0[x + 0] + b0v, 0.f) * kw0 + fmaxf(acc1[x + 0] + b1v, 0.f) * kw1;
        ov.y = iv.y + fmaxf(acc0[x + 1] + b0v, 0.f) * kw0 + fmaxf(acc1[x + 1] + b1v, 0.f) * kw1;
        ov.z = iv.z + fmaxf(acc0[x + 2] + b0v, 0.f) * kw0 + fmaxf(acc1[x + 2] + b1v, 0.f) * kw1;
        ov.w = iv.w + fmaxf(acc0[x + 3] + b0v, 0.f) * kw0 + fmaxf(acc1[x + 3] + b1v, 0.f) * kw1;
        *(float4*)(out + obase + x) = ov;
    }
}

extern "C" void kernel_launch(void* const* d_in, const int* in_sizes, int n_in,
                              void* d_out, int out_size, void* d_ws, size_t ws_size,
                              hipStream_t stream) {
    const float* inputs = (const float*)d_in[0];
    const float* k      = (const float*)d_in[1];
    const float* gate_w = (const float*)d_in[2];
    const float* gate_b = (const float*)d_in[3];
    const float* conv_w = (const float*)d_in[4];
    const float* conv_b = (const float*)d_in[5];
    float* out = (float*)d_out;
    char* wsb = (char*)d_ws;

    if (ws_size >= WS_NEEDED) {
        unsigned short* wT2 = (unsigned short*)wsb;
        float* pooled = (float*)(wsb + OFF_POOL);

        pool_wcvt<<<B_ * C_, 256, 0, stream>>>(inputs, conv_w, pooled, wT2);
        conv_p4<<<1024, 256, 0, stream>>>(inputs, k, conv_b, pooled,
                                          gate_w, gate_b, wT2, out);
    } else {
        float* ws = (float*)d_ws;
        float* wTf    = ws + FB_WT_OFF;
        float* pooled = ws + FB_POOLED_OFF;
        float* ewbuf  = ws + FB_EW_OFF;

        pool_kernel<<<B_ * C_, 256, 0, stream>>>(inputs, pooled);
        gate_kernel<<<1, 64, 0, stream>>>(pooled, gate_w, gate_b, ewbuf);
        wtr_kernel<<<(E_ * C_ * 9 * C_ + 255) / 256, 256, 0, stream>>>(conv_w, wTf);
        conv_fallback<<<B_ * H_, 512, 0, stream>>>(inputs, k, wTf, conv_b, ewbuf, out);
    }
}